// Round 1
// baseline (1898.244 us; speedup 1.0000x reference)
//
#include <hip/hip_runtime.h>
#include <math.h>

#define HH 1024
#define CC 8
#define DD 64
#define FF 32
#define WW 7
#define HP 1018
#define NF 128                    // N*F
#define QSZ (NF*HP*DD)            // 8,339,456 floats per q tensor
#define NRTOT (NF*HP)             // 130,304 rows total

// ---------------- projection (grouped conv) ----------------
// q[n,f,h,d] = sum_{c,j} x[n,h+j,c,d] * W[f,c,d,j]
__global__ __launch_bounds__(256) void conv_kernel(
    const float* __restrict__ x1, const float* __restrict__ x2,
    const float* __restrict__ Wt, float* __restrict__ q1, float* __restrict__ q2)
{
    const float* x = blockIdx.z ? x2 : x1;
    float* q = blockIdx.z ? q2 : q1;
    const int nf = blockIdx.y;
    const int n = nf >> 5, f = nf & 31;
    const int tid = threadIdx.x;
    const int d = tid & 63;
    const int strip = tid >> 6;
    const int h0 = blockIdx.x * 32 + strip * 8;   // 8 outputs per thread

    float w[CC][WW];
#pragma unroll
    for (int c = 0; c < CC; ++c)
#pragma unroll
        for (int j = 0; j < WW; ++j)
            w[c][j] = Wt[((f*CC + c)*DD + d)*WW + j];

    float acc[8];
#pragma unroll
    for (int i = 0; i < 8; ++i) acc[i] = 0.f;

#pragma unroll
    for (int rr = 0; rr < 14; ++rr) {             // rows h0 .. h0+13
        const int row = h0 + rr;
        float xr[CC];
        if (row < HH) {
#pragma unroll
            for (int c = 0; c < CC; ++c)
                xr[c] = x[((size_t)(n*HH + row)*CC + c)*DD + d];
        } else {
#pragma unroll
            for (int c = 0; c < CC; ++c) xr[c] = 0.f;
        }
#pragma unroll
        for (int j = 0; j < WW; ++j) {
            const int i = rr - j;                 // compile-time predicate
            if (i >= 0 && i < 8) {
#pragma unroll
                for (int c = 0; c < CC; ++c)
                    acc[i] = fmaf(xr[c], w[c][j], acc[i]);
            }
        }
    }
#pragma unroll
    for (int i = 0; i < 8; ++i) {
        const int h = h0 + i;
        if (h < HP) q[((size_t)nf*HP + h)*DD + d] = acc[i];
    }
}

// ---------------- pass A: flash attention, p1 = softmax(S)·Q2, save m,l ----------------
// block = 256 threads: r = tid&63 (row in 64-row h-tile), qd = tid>>6 (16-col group)
__global__ __launch_bounds__(256) void flashA(
    const float* __restrict__ q1, const float* __restrict__ q2,
    float* __restrict__ p1, float* __restrict__ mrow, float* __restrict__ lrow,
    float* __restrict__ out)
{
    __shared__ float Q1s[64][65];     // [h][k]
    __shared__ float Q2s[64][68];     // [g][d]  (PV side, float4 over d)
    __shared__ float Q2Ts[64][68];    // [k][g]  (score side, float4 over g)
    __shared__ float Ps[64][65];      // [h][g]
    __shared__ float redm[4][64];
    __shared__ float reds[4][64];

    const int nf = blockIdx.y;
    const int n = nf >> 5, f = nf & 31;
    const int h0 = blockIdx.x * 64;
    const int tid = threadIdx.x;
    const int r = tid & 63;
    const int qd = tid >> 6;

    const float* Q1 = q1 + (size_t)nf * HP * DD;
    const float* Q2 = q2 + (size_t)nf * HP * DD;

    for (int idx = tid; idx < 4096; idx += 256) {
        const int rr = idx >> 6, kk = idx & 63;
        const int h = h0 + rr;
        Q1s[rr][kk] = (h < HP) ? Q1[(size_t)h*DD + kk] : 0.f;
    }

    float m = -1e30f, l = 0.f;
    float O[16];
#pragma unroll
    for (int i = 0; i < 16; ++i) O[i] = 0.f;
    const float scale = 1.0f / 1018.0f;

    for (int g0 = 0; g0 < HP; g0 += 64) {
        __syncthreads();                               // sync1
        for (int idx = tid; idx < 4096; idx += 256) {
            const int rr = idx >> 6, kk = idx & 63;
            const int g = g0 + rr;
            const float v = (g < HP) ? Q2[(size_t)g*DD + kk] : 0.f;
            Q2s[rr][kk] = v;
            Q2Ts[kk][rr] = v;
        }
        __syncthreads();                               // sync2

        float s[16];
#pragma unroll
        for (int i = 0; i < 16; ++i) s[i] = 0.f;
        for (int k = 0; k < 64; ++k) {
            const float a = Q1s[r][k];
            float4 b[4];
            b[0] = *(const float4*)&Q2Ts[k][qd*16 + 0];
            b[1] = *(const float4*)&Q2Ts[k][qd*16 + 4];
            b[2] = *(const float4*)&Q2Ts[k][qd*16 + 8];
            b[3] = *(const float4*)&Q2Ts[k][qd*16 + 12];
#pragma unroll
            for (int ii = 0; ii < 4; ++ii) {
                s[4*ii+0] = fmaf(a, b[ii].x, s[4*ii+0]);
                s[4*ii+1] = fmaf(a, b[ii].y, s[4*ii+1]);
                s[4*ii+2] = fmaf(a, b[ii].z, s[4*ii+2]);
                s[4*ii+3] = fmaf(a, b[ii].w, s[4*ii+3]);
            }
        }

        float lmax = -1e30f;
#pragma unroll
        for (int i = 0; i < 16; ++i) {
            const int g = g0 + qd*16 + i;
            s[i] = (g < HP) ? s[i] * scale : -1e30f;
            lmax = fmaxf(lmax, s[i]);
        }
        redm[qd][r] = lmax;
        __syncthreads();                               // sync3
        const float rowmax = fmaxf(fmaxf(redm[0][r], redm[1][r]),
                                   fmaxf(redm[2][r], redm[3][r]));
        const float mnew = fmaxf(m, rowmax);
        const float alpha = __expf(m - mnew);
        float lsum = 0.f;
#pragma unroll
        for (int i = 0; i < 16; ++i) {
            s[i] = __expf(s[i] - mnew);
            lsum += s[i];
        }
#pragma unroll
        for (int i = 0; i < 16; ++i) Ps[r][qd*16 + i] = s[i];
        reds[qd][r] = lsum;
        __syncthreads();                               // sync4
        l = l * alpha + (reds[0][r] + reds[1][r] + reds[2][r] + reds[3][r]);
        m = mnew;
#pragma unroll
        for (int i = 0; i < 16; ++i) O[i] *= alpha;
        for (int g = 0; g < 64; ++g) {
            const float p = Ps[r][g];
            float4 v[4];
            v[0] = *(const float4*)&Q2s[g][qd*16 + 0];
            v[1] = *(const float4*)&Q2s[g][qd*16 + 4];
            v[2] = *(const float4*)&Q2s[g][qd*16 + 8];
            v[3] = *(const float4*)&Q2s[g][qd*16 + 12];
#pragma unroll
            for (int ii = 0; ii < 4; ++ii) {
                O[4*ii+0] = fmaf(p, v[ii].x, O[4*ii+0]);
                O[4*ii+1] = fmaf(p, v[ii].y, O[4*ii+1]);
                O[4*ii+2] = fmaf(p, v[ii].z, O[4*ii+2]);
                O[4*ii+3] = fmaf(p, v[ii].w, O[4*ii+3]);
            }
        }
    }

    const int h = h0 + r;
    if (h < HP) {
        const float linv = 1.f / l;
        float* prow = p1 + ((size_t)nf*HP + h)*DD + qd*16;
        float* orow = out + (((size_t)(n*HP + h))*FF + f)*DD + qd*16;
#pragma unroll
        for (int j = 0; j < 16; ++j) {
            const float v = O[j] * linv;
            prow[j] = v;
            orow[j] = tanhf(v);
        }
        if (qd == 0) {
            mrow[(size_t)nf*HP + h] = m;
            lrow[(size_t)nf*HP + h] = l;
        }
    }
}

// ---------------- pass B: p2 = a · p1, a = exp(S - m)/l with stored m,l ----------------
__global__ __launch_bounds__(256) void flashB(
    const float* __restrict__ q1, const float* __restrict__ q2,
    const float* __restrict__ p1, const float* __restrict__ mrow,
    const float* __restrict__ lrow, float* __restrict__ out)
{
    __shared__ float Q1s[64][65];
    __shared__ float Q2Ts[64][68];    // [k][g]
    __shared__ float Vs[64][68];      // [g][d] = p1 tile
    __shared__ float Ps[64][65];

    const int nf = blockIdx.y;
    const int n = nf >> 5, f = nf & 31;
    const int h0 = blockIdx.x * 64;
    const int tid = threadIdx.x;
    const int r = tid & 63;
    const int qd = tid >> 6;

    const float* Q1 = q1 + (size_t)nf * HP * DD;
    const float* Q2 = q2 + (size_t)nf * HP * DD;
    const float* V  = p1 + (size_t)nf * HP * DD;

    for (int idx = tid; idx < 4096; idx += 256) {
        const int rr = idx >> 6, kk = idx & 63;
        const int h = h0 + rr;
        Q1s[rr][kk] = (h < HP) ? Q1[(size_t)h*DD + kk] : 0.f;
    }
    __syncthreads();

    const int h = h0 + r;
    const float m    = (h < HP) ? mrow[(size_t)nf*HP + h] : 0.f;
    const float linv = (h < HP) ? 1.f / lrow[(size_t)nf*HP + h] : 0.f;

    float O[16];
#pragma unroll
    for (int i = 0; i < 16; ++i) O[i] = 0.f;
    const float scale = 1.0f / 1018.0f;

    for (int g0 = 0; g0 < HP; g0 += 64) {
        __syncthreads();                               // sync1
        for (int idx = tid; idx < 4096; idx += 256) {
            const int rr = idx >> 6, kk = idx & 63;
            const int g = g0 + rr;
            Q2Ts[kk][rr] = (g < HP) ? Q2[(size_t)g*DD + kk] : 0.f;
            Vs[rr][kk]   = (g < HP) ? V[(size_t)g*DD + kk] : 0.f;
        }
        __syncthreads();                               // sync2

        float s[16];
#pragma unroll
        for (int i = 0; i < 16; ++i) s[i] = 0.f;
        for (int k = 0; k < 64; ++k) {
            const float a = Q1s[r][k];
            float4 b[4];
            b[0] = *(const float4*)&Q2Ts[k][qd*16 + 0];
            b[1] = *(const float4*)&Q2Ts[k][qd*16 + 4];
            b[2] = *(const float4*)&Q2Ts[k][qd*16 + 8];
            b[3] = *(const float4*)&Q2Ts[k][qd*16 + 12];
#pragma unroll
            for (int ii = 0; ii < 4; ++ii) {
                s[4*ii+0] = fmaf(a, b[ii].x, s[4*ii+0]);
                s[4*ii+1] = fmaf(a, b[ii].y, s[4*ii+1]);
                s[4*ii+2] = fmaf(a, b[ii].z, s[4*ii+2]);
                s[4*ii+3] = fmaf(a, b[ii].w, s[4*ii+3]);
            }
        }
#pragma unroll
        for (int i = 0; i < 16; ++i) {
            const int g = g0 + qd*16 + i;
            s[i] = (g < HP) ? __expf(s[i]*scale - m) : 0.f;
        }
#pragma unroll
        for (int i = 0; i < 16; ++i) Ps[r][qd*16 + i] = s[i];
        __syncthreads();                               // sync3
        for (int g = 0; g < 64; ++g) {
            const float p = Ps[r][g];
            float4 v[4];
            v[0] = *(const float4*)&Vs[g][qd*16 + 0];
            v[1] = *(const float4*)&Vs[g][qd*16 + 4];
            v[2] = *(const float4*)&Vs[g][qd*16 + 8];
            v[3] = *(const float4*)&Vs[g][qd*16 + 12];
#pragma unroll
            for (int ii = 0; ii < 4; ++ii) {
                O[4*ii+0] = fmaf(p, v[ii].x, O[4*ii+0]);
                O[4*ii+1] = fmaf(p, v[ii].y, O[4*ii+1]);
                O[4*ii+2] = fmaf(p, v[ii].z, O[4*ii+2]);
                O[4*ii+3] = fmaf(p, v[ii].w, O[4*ii+3]);
            }
        }
    }

    if (h < HP) {
        float* orow = out + (((size_t)(n*HP + h))*FF + f)*DD + qd*16;
#pragma unroll
        for (int j = 0; j < 16; ++j)
            orow[j] = tanhf(O[j] * linv);
    }
}

extern "C" void kernel_launch(void* const* d_in, const int* in_sizes, int n_in,
                              void* d_out, int out_size, void* d_ws, size_t ws_size,
                              hipStream_t stream)
{
    const float* prot1 = (const float*)d_in[0];
    const float* prot2 = (const float*)d_in[1];
    const float* Wt    = (const float*)d_in[2];
    float* out = (float*)d_out;
    float* ws  = (float*)d_ws;

    float* q1   = ws;                 // QSZ
    float* q2   = q1 + QSZ;           // QSZ
    float* p1   = q2 + QSZ;           // QSZ
    float* mrow = p1 + QSZ;           // NRTOT
    float* lrow = mrow + NRTOT;       // NRTOT
    // total ws use: (3*QSZ + 2*NRTOT)*4 bytes ≈ 96.4 MiB

    conv_kernel<<<dim3(32, NF, 2), 256, 0, stream>>>(prot1, prot2, Wt, q1, q2);
    flashA<<<dim3(16, NF), 256, 0, stream>>>(q1, q2, p1, mrow, lrow, out);
    flashB<<<dim3(16, NF), 256, 0, stream>>>(q1, q2, p1, mrow, lrow, out + QSZ);
}

// Round 2
// 233.300 us; speedup vs baseline: 8.1365x; 8.1365x over previous
//
#include <hip/hip_runtime.h>
#include <math.h>

typedef __bf16 bf16_t;
typedef bf16_t bf16x4 __attribute__((ext_vector_type(4)));
typedef bf16_t bf16x8 __attribute__((ext_vector_type(8)));
typedef float  f32x16 __attribute__((ext_vector_type(16)));

#define HH 1024
#define CC 8
#define DD 64
#define FF 32
#define WW 7
#define HP 1018
#define HPAD 1024
#define NF 128
#define QOUT (NF*HP*DD)                 // 8,339,456 out elements per tensor
#define QWS ((size_t)NF*HPAD*DD)        // bf16 elements per ws tensor

// ---------------- projection (grouped conv), bf16 output, zero-padded to HPAD rows ----
__global__ __launch_bounds__(256) void conv_kernel(
    const float* __restrict__ x1, const float* __restrict__ x2,
    const float* __restrict__ Wt, bf16_t* __restrict__ q1, bf16_t* __restrict__ q2)
{
    const float* x = blockIdx.z ? x2 : x1;
    bf16_t* q = blockIdx.z ? q2 : q1;
    const int nf = blockIdx.y;
    const int n = nf >> 5, f = nf & 31;
    const int tid = threadIdx.x;
    const int d = tid & 63;
    const int strip = tid >> 6;
    const int h0 = blockIdx.x * 32 + strip * 8;   // 8 outputs per thread, covers h<1024

    float w[CC][WW];
#pragma unroll
    for (int c = 0; c < CC; ++c)
#pragma unroll
        for (int j = 0; j < WW; ++j)
            w[c][j] = Wt[((f*CC + c)*DD + d)*WW + j];

    float acc[8];
#pragma unroll
    for (int i = 0; i < 8; ++i) acc[i] = 0.f;

#pragma unroll
    for (int rr = 0; rr < 14; ++rr) {
        const int row = h0 + rr;
        float xr[CC];
        if (row < HH) {
#pragma unroll
            for (int c = 0; c < CC; ++c)
                xr[c] = x[((size_t)(n*HH + row)*CC + c)*DD + d];
        } else {
#pragma unroll
            for (int c = 0; c < CC; ++c) xr[c] = 0.f;
        }
#pragma unroll
        for (int j = 0; j < WW; ++j) {
            const int i = rr - j;
            if (i >= 0 && i < 8) {
#pragma unroll
                for (int c = 0; c < CC; ++c)
                    acc[i] = fmaf(xr[c], w[c][j], acc[i]);
            }
        }
    }
#pragma unroll
    for (int i = 0; i < 8; ++i) {
        const int h = h0 + i;
        const float v = (h < HP) ? acc[i] : 0.f;   // zero-pad rows HP..HPAD-1
        q[((size_t)nf*HPAD + h)*DD + d] = (bf16_t)v;
    }
}

__device__ __forceinline__ float fast_tanh(float x) {
    const float t = __expf(2.f * x);
    return (t - 1.f) / (t + 1.f);
}

// ---------------- fused flash pass (MFMA) ----------------
// MODE 0: V = q2, writes p1 (bf16) + out1 = tanh(p1)
// MODE 1: V = p1, writes out2 = tanh(p2)
// Sᵀ = Q2·Q1ᵀ so that C-layout col (lane&31) = output row h.
// C/D layout (m74/m101): col=lane&31, row=(reg&3)+8*(reg>>2)+4*(lane>>5).
template<int MODE>
__global__ __launch_bounds__(256, 2) void flash(
    const bf16_t* __restrict__ q1, const bf16_t* __restrict__ q2,
    const bf16_t* __restrict__ vsrc, bf16_t* __restrict__ p1out,
    float* __restrict__ out)
{
    __shared__ bf16_t As[64*68];   // q2 tile [g][d], stride 68 (2-way bank alias = free)
    __shared__ bf16_t Vt[64*68];   // V^T tile [d][g], stride 68

    const int head = blockIdx.y;
    const int n = head >> 5, f = head & 31;
    const int tid = threadIdx.x;
    const int w = tid >> 6;
    const int lane = tid & 63;
    const int lid = lane & 31;
    const int half = lane >> 5;
    const int hb = blockIdx.x * 256 + w * 64;   // wave h-base (64 rows per wave)

    const size_t qoff = (size_t)head * HPAD * DD;
    const float SCALE = 1.f / 1018.f;

    // Q1 B-fragments, persistent in registers: B[k=d][n=h], k = 8*half + j
    bf16x8 bq1[2][4];
#pragma unroll
    for (int nt = 0; nt < 2; ++nt)
#pragma unroll
        for (int kt = 0; kt < 4; ++kt)
            bq1[nt][kt] = *(const bf16x8*)&q1[qoff + (size_t)(hb + 32*nt + lid)*DD + 16*kt + 8*half];

    f32x16 O[2][2] = {};     // [ht][dt] accumulators (unnormalized p)
    float lacc[2] = {0.f, 0.f};

    for (int g0 = 0; g0 < HPAD; g0 += 64) {
        __syncthreads();
        // ---- stage KV tile: As=[g][d], Vt=[d][g] (register transpose, b64 writes) ----
        {
            const int gq = tid >> 4;    // 0..15 -> rows 4gq..4gq+3
            const int dq = tid & 15;    // 0..15 -> cols 4dq..4dq+3
            bf16x4 r[4];
#pragma unroll
            for (int i = 0; i < 4; ++i) {
                r[i] = *(const bf16x4*)&q2[qoff + (size_t)(g0 + 4*gq + i)*DD + 4*dq];
                *(bf16x4*)&As[(4*gq + i)*68 + 4*dq] = r[i];
            }
            if (MODE == 1) {
#pragma unroll
                for (int i = 0; i < 4; ++i)
                    r[i] = *(const bf16x4*)&vsrc[qoff + (size_t)(g0 + 4*gq + i)*DD + 4*dq];
            }
#pragma unroll
            for (int j = 0; j < 4; ++j) {
                bf16x4 c = { r[0][j], r[1][j], r[2][j], r[3][j] };
                *(bf16x4*)&Vt[(4*dq + j)*68 + 4*gq] = c;
            }
        }
        __syncthreads();

        const bool tail = (g0 + 64 > HP);

#pragma unroll
        for (int mt = 0; mt < 2; ++mt) {
            // ---- S-phase: C[nt] = Q2tile(32g x 64d) · Q1^T ----
            f32x16 C[2] = {};
#pragma unroll
            for (int kt = 0; kt < 4; ++kt) {
                const int ab = (32*mt + lid)*68 + 16*kt + 8*half;
                bf16x4 a0 = *(const bf16x4*)&As[ab];
                bf16x4 a1 = *(const bf16x4*)&As[ab + 4];
                bf16x8 a = {a0[0],a0[1],a0[2],a0[3],a1[0],a1[1],a1[2],a1[3]};
                C[0] = __builtin_amdgcn_mfma_f32_32x32x16_bf16(a, bq1[0][kt], C[0], 0,0,0);
                C[1] = __builtin_amdgcn_mfma_f32_32x32x16_bf16(a, bq1[1][kt], C[1], 0,0,0);
            }
            // ---- exp (max-free softmax) + pack PV A-frags from C-regs ----
            bf16x8 af[2][2];   // [ht][u], u = 16-wide k-window within this mt
#pragma unroll
            for (int nt = 0; nt < 2; ++nt) {
                float ls = 0.f;
#pragma unroll
                for (int s = 0; s < 16; ++s) {
                    float e = __expf(C[nt][s] * SCALE);
                    if (tail) {
                        const int gg = g0 + 32*mt + (s&3) + 8*(s>>2) + 4*half;
                        if (gg >= HP) e = 0.f;
                    }
                    ls += e;
                    af[nt][s>>3][s&7] = (bf16_t)e;
                }
                lacc[nt] += ls;
            }
            // ---- PV: O[ht][dt] += P^T(frag) · V ----
            // B-side k-permutation matches C-reg order: g = 32mt + 16u + (j&3)+8*(j>>2)+4*half
#pragma unroll
            for (int u = 0; u < 2; ++u) {
#pragma unroll
                for (int dt = 0; dt < 2; ++dt) {
                    const int vb = (32*dt + lid)*68 + 32*mt + 16*u + 4*half;
                    bf16x4 b0 = *(const bf16x4*)&Vt[vb];
                    bf16x4 b1 = *(const bf16x4*)&Vt[vb + 8];
                    bf16x8 b = {b0[0],b0[1],b0[2],b0[3],b1[0],b1[1],b1[2],b1[3]};
                    O[0][dt] = __builtin_amdgcn_mfma_f32_32x32x16_bf16(af[0][u], b, O[0][dt], 0,0,0);
                    O[1][dt] = __builtin_amdgcn_mfma_f32_32x32x16_bf16(af[1][u], b, O[1][dt], 0,0,0);
                }
            }
        }
    }

    // ---- epilogue: l reduction, normalize, tanh, store ----
    float linv[2];
#pragma unroll
    for (int nt = 0; nt < 2; ++nt) {
        const float l = lacc[nt] + __shfl_xor(lacc[nt], 32);
        linv[nt] = 1.f / l;
    }
#pragma unroll
    for (int ht = 0; ht < 2; ++ht) {
#pragma unroll
        for (int s = 0; s < 16; ++s) {
            const int R = (s&3) + 8*(s>>2) + 4*half;
            const float li = __shfl(linv[ht], R);
            const int hg = hb + 32*ht + R;
            if (hg < HP) {
#pragma unroll
                for (int dt = 0; dt < 2; ++dt) {
                    const int d = 32*dt + lid;
                    const float val = O[ht][dt][s] * li;
                    out[(((size_t)n*HP + hg)*FF + f)*DD + d] = fast_tanh(val);
                    if (MODE == 0)
                        p1out[qoff + (size_t)hg*DD + d] = (bf16_t)val;
                }
            }
        }
    }
}

extern "C" void kernel_launch(void* const* d_in, const int* in_sizes, int n_in,
                              void* d_out, int out_size, void* d_ws, size_t ws_size,
                              hipStream_t stream)
{
    const float* prot1 = (const float*)d_in[0];
    const float* prot2 = (const float*)d_in[1];
    const float* Wt    = (const float*)d_in[2];
    float* out = (float*)d_out;

    bf16_t* q1b = (bf16_t*)d_ws;          // QWS bf16
    bf16_t* q2b = q1b + QWS;              // QWS bf16
    bf16_t* p1b = q2b + QWS;              // QWS bf16  (total 48 MiB)

    conv_kernel<<<dim3(32, NF, 2), 256, 0, stream>>>(prot1, prot2, Wt, q1b, q2b);
    flash<0><<<dim3(4, NF), 256, 0, stream>>>(q1b, q2b, q2b, p1b, out);
    flash<1><<<dim3(4, NF), 256, 0, stream>>>(q1b, q2b, p1b, p1b, out + QOUT);
}

// Round 3
// 224.531 us; speedup vs baseline: 8.4543x; 1.0391x over previous
//
#include <hip/hip_runtime.h>
#include <math.h>

typedef __bf16 bf16_t;
typedef bf16_t bf16x4 __attribute__((ext_vector_type(4)));
typedef bf16_t bf16x8 __attribute__((ext_vector_type(8)));
typedef float  f32x16 __attribute__((ext_vector_type(16)));

#define HH 1024
#define CC 8
#define DD 64
#define FF 32
#define WW 7
#define HP 1018
#define HPAD 1024
#define NF 128
#define QOUT (NF*HP*DD)
#define QWS ((size_t)NF*HPAD*DD)
#define LSTR 72                          // LDS row stride (bf16): 144 B, 16B-aligned, uniform banks

#if __has_builtin(__builtin_amdgcn_exp2f)
#define EXP2(x) __builtin_amdgcn_exp2f(x)
#else
#define EXP2(x) __expf((x) * 0.6931471805599453f)
#endif

// ---------------- W transpose: Wt[f][c][d][j] -> Wp[f][c][j][d] ----------------
__global__ __launch_bounds__(256) void wprep_kernel(
    const float* __restrict__ Wt, float* __restrict__ Wp)
{
    const int idx = blockIdx.x * 256 + threadIdx.x;
    if (idx < FF*CC*DD*WW) {
        const int j = idx % WW;
        int t = idx / WW;
        const int d = t % DD; t /= DD;
        const int c = t % CC;
        const int f = t / CC;
        Wp[((f*CC + c)*WW + j)*DD + d] = Wt[idx];
    }
}

// ---------------- projection (grouped conv) v2: all f per block, x staged in LDS ----
__global__ __launch_bounds__(256) void conv_kernel(
    const float* __restrict__ x1, const float* __restrict__ x2,
    const float* __restrict__ Wp, bf16_t* __restrict__ q1, bf16_t* __restrict__ q2)
{
    __shared__ float xs[38*512];          // rows hb..hb+37, [row][c][d] fp32, 77824 B
    const float* x = blockIdx.z ? x2 : x1;
    bf16_t* q = blockIdx.z ? q2 : q1;
    const int n = blockIdx.y;
    const int hb = blockIdx.x * 32;
    const int tid = threadIdx.x;

    const float4* xg = (const float4*)(x + (size_t)n*HH*512);
    for (int i = tid; i < 38*128; i += 256) {
        const int row = hb + (i >> 7);
        float4 v = {0.f, 0.f, 0.f, 0.f};
        if (row < HH) v = xg[(size_t)row*128 + (i & 127)];
        *(float4*)&xs[(size_t)i*4] = v;
    }
    __syncthreads();

    const int d = tid & 63;
    const int fq = tid >> 6;
    for (int fi = 0; fi < 8; ++fi) {
        const int f = fq*8 + fi;
        float w[CC][WW];
#pragma unroll
        for (int c = 0; c < CC; ++c)
#pragma unroll
            for (int j = 0; j < WW; ++j)
                w[c][j] = Wp[((f*CC + c)*WW + j)*DD + d];
#pragma unroll
        for (int hc = 0; hc < 2; ++hc) {
            float acc[16];
#pragma unroll
            for (int i = 0; i < 16; ++i) acc[i] = 0.f;
#pragma unroll
            for (int rr = 0; rr < 22; ++rr) {
                float xv[CC];
#pragma unroll
                for (int c = 0; c < CC; ++c)
                    xv[c] = xs[(hc*16 + rr)*512 + c*64 + d];
#pragma unroll
                for (int j = 0; j < WW; ++j) {
                    const int i = rr - j;
                    if (i >= 0 && i < 16) {
#pragma unroll
                        for (int c = 0; c < CC; ++c)
                            acc[i] = fmaf(xv[c], w[c][j], acc[i]);
                    }
                }
            }
#pragma unroll
            for (int i = 0; i < 16; ++i) {
                const int h = hb + hc*16 + i;
                const float v = (h < HP) ? acc[i] : 0.f;   // zero-pad rows HP..HPAD-1
                q[((size_t)(n*FF + f)*HPAD + h)*DD + d] = (bf16_t)v;
            }
        }
    }
}

__device__ __forceinline__ float fast_tanh(float x) {
    const float t = __expf(2.f * x);
    return (t - 1.f) / (t + 1.f);
}

// ---------------- fused flash pass (MFMA) ----------------
// Sᵀ = Q2·Q1ᵀ so C-layout col (lane&31) = output row h.
// C/D layout (m74/m101): col=lane&31, row=(reg&3)+8*(reg>>2)+4*(lane>>5).
// Vt columns stored in PERMUTED order p(g) = (g&3) + 4*bit3(g) + 8*bit2(g) + 16*(g>>4)
// so each PV B-frag (matching C-reg k-order) is 8 contiguous bf16 -> one ds_read_b128.
template<int MODE>
__global__ __launch_bounds__(256, 2) void flash(
    const bf16_t* __restrict__ q1, const bf16_t* __restrict__ q2,
    const bf16_t* __restrict__ vsrc, bf16_t* __restrict__ p1out,
    float* __restrict__ out)
{
    __shared__ __align__(16) bf16_t As[64*LSTR];   // q2 tile [g][d]
    __shared__ __align__(16) bf16_t Vt[64*LSTR];   // V^T tile [d][p(g)]

    const int head = blockIdx.y;
    const int n = head >> 5, f = head & 31;
    const int tid = threadIdx.x;
    const int w = tid >> 6;
    const int lane = tid & 63;
    const int lid = lane & 31;
    const int half = lane >> 5;
    const int hb = blockIdx.x * 256 + w * 64;

    const size_t qoff = (size_t)head * HPAD * DD;
    const float SC = 1.442695041f / 1018.f;        // log2(e)/1018

    // staging map: thread loads rows g=4gq..4gq+3, cols 4dq..4dq+3
    const int gq = tid >> 4;
    const int dq = tid & 15;
    const int cgb = 4*((gq>>1)&1) + 8*(gq&1) + 16*(gq>>2);   // permuted col base for Vt

    // Q1 B-fragments, persistent in registers
    bf16x8 bq1[2][4];
#pragma unroll
    for (int nt = 0; nt < 2; ++nt)
#pragma unroll
        for (int kt = 0; kt < 4; ++kt)
            bq1[nt][kt] = *(const bf16x8*)&q1[qoff + (size_t)(hb + 32*nt + lid)*DD + 16*kt + 8*half];

    f32x16 O[2][2] = {};
    float lacc[2] = {0.f, 0.f};

    // register preload of tile 0
    bf16x4 rA[4], rV[4];
#pragma unroll
    for (int i = 0; i < 4; ++i) {
        rA[i] = *(const bf16x4*)&q2[qoff + (size_t)(4*gq + i)*DD + 4*dq];
        if (MODE == 1)
            rV[i] = *(const bf16x4*)&vsrc[qoff + (size_t)(4*gq + i)*DD + 4*dq];
    }

    for (int g0 = 0; g0 < HPAD; g0 += 64) {
        __syncthreads();                           // prev tile fully consumed
        // ---- write staged regs to LDS ----
#pragma unroll
        for (int i = 0; i < 4; ++i)
            *(bf16x4*)&As[(4*gq + i)*LSTR + 4*dq] = rA[i];
        {
            const bf16x4* rv = (MODE == 1) ? rV : rA;
#pragma unroll
            for (int j = 0; j < 4; ++j) {
                bf16x4 c = { rv[0][j], rv[1][j], rv[2][j], rv[3][j] };
                *(bf16x4*)&Vt[(4*dq + j)*LSTR + cgb] = c;
            }
        }
        __syncthreads();

        // ---- preload next tile (latency hidden under compute) ----
        if (g0 + 64 < HPAD) {
            const int gn = g0 + 64;
#pragma unroll
            for (int i = 0; i < 4; ++i) {
                rA[i] = *(const bf16x4*)&q2[qoff + (size_t)(gn + 4*gq + i)*DD + 4*dq];
                if (MODE == 1)
                    rV[i] = *(const bf16x4*)&vsrc[qoff + (size_t)(gn + 4*gq + i)*DD + 4*dq];
            }
        }

        const bool tail = (g0 + 64 > HP);

#pragma unroll
        for (int mt = 0; mt < 2; ++mt) {
            // ---- S-phase ----
            f32x16 C[2] = {};
#pragma unroll
            for (int kt = 0; kt < 4; ++kt) {
                bf16x8 a = *(const bf16x8*)&As[(32*mt + lid)*LSTR + 16*kt + 8*half];
                C[0] = __builtin_amdgcn_mfma_f32_32x32x16_bf16(a, bq1[0][kt], C[0], 0,0,0);
                C[1] = __builtin_amdgcn_mfma_f32_32x32x16_bf16(a, bq1[1][kt], C[1], 0,0,0);
            }
            // ---- exp + pack PV A-frags ----
            bf16x8 af[2][2];
#pragma unroll
            for (int nt = 0; nt < 2; ++nt) {
                float ls = 0.f;
#pragma unroll
                for (int s = 0; s < 16; ++s) {
                    float e = EXP2(C[nt][s] * SC);
                    if (tail) {
                        const int gg = g0 + 32*mt + (s&3) + 8*(s>>2) + 4*half;
                        if (gg >= HP) e = 0.f;
                    }
                    ls += e;
                    af[nt][s>>3][s&7] = (bf16_t)e;
                }
                lacc[nt] += ls;
            }
            // ---- PV: B-frag is contiguous thanks to permuted Vt layout ----
#pragma unroll
            for (int u = 0; u < 2; ++u) {
#pragma unroll
                for (int dt = 0; dt < 2; ++dt) {
                    bf16x8 b = *(const bf16x8*)&Vt[(32*dt + lid)*LSTR + 32*mt + 16*u + 8*half];
                    O[0][dt] = __builtin_amdgcn_mfma_f32_32x32x16_bf16(af[0][u], b, O[0][dt], 0,0,0);
                    O[1][dt] = __builtin_amdgcn_mfma_f32_32x32x16_bf16(af[1][u], b, O[1][dt], 0,0,0);
                }
            }
        }
    }

    // ---- epilogue ----
    float linv[2];
#pragma unroll
    for (int nt = 0; nt < 2; ++nt) {
        const float l = lacc[nt] + __shfl_xor(lacc[nt], 32);
        linv[nt] = 1.f / l;
    }
#pragma unroll
    for (int ht = 0; ht < 2; ++ht) {
#pragma unroll
        for (int s = 0; s < 16; ++s) {
            const int R = (s&3) + 8*(s>>2) + 4*half;
            const float li = __shfl(linv[ht], R);
            const int hg = hb + 32*ht + R;
            if (hg < HP) {
#pragma unroll
                for (int dt = 0; dt < 2; ++dt) {
                    const int d = 32*dt + lid;
                    const float val = O[ht][dt][s] * li;
                    out[(((size_t)n*HP + hg)*FF + f)*DD + d] = fast_tanh(val);
                    if (MODE == 0)
                        p1out[qoff + (size_t)hg*DD + d] = (bf16_t)val;
                }
            }
        }
    }
}

extern "C" void kernel_launch(void* const* d_in, const int* in_sizes, int n_in,
                              void* d_out, int out_size, void* d_ws, size_t ws_size,
                              hipStream_t stream)
{
    const float* prot1 = (const float*)d_in[0];
    const float* prot2 = (const float*)d_in[1];
    const float* Wt    = (const float*)d_in[2];
    float* out = (float*)d_out;

    bf16_t* q1b = (bf16_t*)d_ws;          // QWS bf16
    bf16_t* q2b = q1b + QWS;
    bf16_t* p1b = q2b + QWS;
    float* Wp   = (float*)(p1b + QWS);    // 114688 floats

    wprep_kernel<<<dim3(448), 256, 0, stream>>>(Wt, Wp);
    conv_kernel<<<dim3(32, 4, 2), 256, 0, stream>>>(prot1, prot2, Wp, q1b, q2b);
    flash<0><<<dim3(4, NF), 256, 0, stream>>>(q1b, q2b, q2b, p1b, out);
    flash<1><<<dim3(4, NF), 256, 0, stream>>>(q1b, q2b, p1b, p1b, out + QOUT);
}